// Round 1
// baseline (31708.450 us; speedup 1.0000x reference)
//
#include <hip/hip_runtime.h>
#include <hip/hip_bf16.h>

// Problem constants
#define BB   4096
#define LL   36
#define DD   128
#define DFF  512
#define ELAYERS 8
#define MROW (BB*LL)           // 147456
#define SFL  ((size_t)BB*LL*DD) // 18874368 floats per [B,L,D] buffer

__device__ __forceinline__ float gelu_exact(float x) {
  return 0.5f * x * (1.0f + erff(x * 0.70710678118654752f));
}

// ---------------------------------------------------------------------------
// Generic fp32 GEMM: C[M,N] = act(A[M,K] @ B[K,N] + bias)
// 64x64 tile, BK=16, 256 threads, 4x4 micro-tile per thread.
// ACT: 0 = none, 1 = exact GELU
// ---------------------------------------------------------------------------
template<int ACT>
__global__ __launch_bounds__(256)
void gemm_f32(const float* __restrict__ A, const float* __restrict__ B,
              const float* __restrict__ bias, float* __restrict__ C,
              int M, int N, int K) {
  __shared__ float As[16][68];  // stride 68 floats = 272B -> 16B-aligned rows
  __shared__ float Bs[16][68];
  const int bm = blockIdx.y * 64, bn = blockIdx.x * 64;
  const int tid = threadIdx.x;
  const int tr = tid >> 4, tc = tid & 15;
  float acc[4][4] = {};
  for (int k0 = 0; k0 < K; k0 += 16) {
#pragma unroll
    for (int i = 0; i < 4; i++) {
      int idx = tid + i * 256;
      int m  = idx >> 4, kk = idx & 15;
      float va = 0.f;
      if (bm + m < M && k0 + kk < K) va = A[(size_t)(bm + m) * K + k0 + kk];
      As[kk][m] = va;
      int kk2 = idx >> 6, n = idx & 63;
      float vb = 0.f;
      if (k0 + kk2 < K && bn + n < N) vb = B[(size_t)(k0 + kk2) * N + bn + n];
      Bs[kk2][n] = vb;
    }
    __syncthreads();
#pragma unroll
    for (int kk = 0; kk < 16; kk++) {
      const float4 av = *(const float4*)&As[kk][tr * 4];
      const float4 bv = *(const float4*)&Bs[kk][tc * 4];
      const float a4[4] = {av.x, av.y, av.z, av.w};
      const float b4[4] = {bv.x, bv.y, bv.z, bv.w};
#pragma unroll
      for (int i = 0; i < 4; i++)
#pragma unroll
        for (int j = 0; j < 4; j++)
          acc[i][j] += a4[i] * b4[j];
    }
    __syncthreads();
  }
#pragma unroll
  for (int i = 0; i < 4; i++) {
    int m = bm + tr * 4 + i;
    if (m >= M) continue;
#pragma unroll
    for (int j = 0; j < 4; j++) {
      int n = bn + tc * 4 + j;
      if (n >= N) continue;
      float v = acc[i][j];
      if (bias) v += bias[n];
      if (ACT == 1) v = gelu_exact(v);
      C[(size_t)m * N + n] = v;
    }
  }
}

// ---------------------------------------------------------------------------
// Autocorrelation block (inference path). One block per batch sample.
// corr[tau] = sum_s q[(s+tau)%L,:] . k[s,:]  (mean over D included)
// top-3 delays -> softmax weights -> agg[t,:] = sum_i w_i * v[(t+d_i)%L,:]
// agg may alias q (q fully read into LDS before any global write).
// ---------------------------------------------------------------------------
__global__ __launch_bounds__(256)
void autocorr_kernel(const float* __restrict__ q, const float* __restrict__ k,
                     const float* __restrict__ v, float* __restrict__ agg) {
  const int b = blockIdx.x;
  const float* qb = q + (size_t)b * LL * DD;
  const float* kb = k + (size_t)b * LL * DD;
  const float* vb = v + (size_t)b * LL * DD;
  __shared__ float qs[LL][129];
  __shared__ float ks[LL][129];
  __shared__ float G[LL][37];    // G[s2][s] = q[s2] . k[s]
  __shared__ float mv[LL];
  __shared__ float wts[3];
  __shared__ int   dly[3];
  const int tid = threadIdx.x;

  for (int p = tid; p < LL * DD; p += 256) {
    int t = p >> 7, d = p & 127;
    qs[t][d] = qb[p];
    ks[t][d] = kb[p];
  }
  __syncthreads();

  for (int p = tid; p < LL * LL; p += 256) {
    int s2 = p / LL, s = p % LL;
    float acc = 0.f;
#pragma unroll 8
    for (int d = 0; d < DD; d++) acc += qs[s2][d] * ks[s][d];
    G[s2][s] = acc;
  }
  __syncthreads();

  if (tid < LL) {
    float acc = 0.f;
    for (int s = 0; s < LL; s++) acc += G[(s + tid) % LL][s];
    mv[tid] = acc * (1.0f / 128.0f);
  }
  __syncthreads();

  if (tid == 0) {
    int d0 = -1, d1 = -1, d2 = -1;
    float v0 = -1e30f, v1 = -1e30f, v2 = -1e30f;
    for (int t = 0; t < LL; t++) {
      float x = mv[t];
      if (x > v0)      { v2 = v1; d2 = d1; v1 = v0; d1 = d0; v0 = x; d0 = t; }
      else if (x > v1) { v2 = v1; d2 = d1; v1 = x;  d1 = t; }
      else if (x > v2) { v2 = x;  d2 = t; }
    }
    float e0 = 1.0f, e1 = expf(v1 - v0), e2 = expf(v2 - v0);
    float inv = 1.0f / (e0 + e1 + e2);
    wts[0] = e0 * inv; wts[1] = e1 * inv; wts[2] = e2 * inv;
    dly[0] = d0; dly[1] = d1; dly[2] = d2;
  }
  __syncthreads();

  const float w0 = wts[0], w1 = wts[1], w2 = wts[2];
  const int  e0 = dly[0], e1 = dly[1], e2 = dly[2];
  float* ab = agg + (size_t)b * LL * DD;
  for (int p = tid; p < LL * DD; p += 256) {
    int t = p >> 7, d = p & 127;
    float r = w0 * vb[((t + e0) % LL) * DD + d]
            + w1 * vb[((t + e1) % LL) * DD + d]
            + w2 * vb[((t + e2) % LL) * DD + d];
    ab[p] = r;
  }
}

// ---------------------------------------------------------------------------
// Fused residual add + series decomposition: h = (h+a) - movavg25(h+a)
// movavg: window 25, edge-replicate pad 12. One thread per (b,d) time-column.
// In-place safe (thread owns its whole column).
// ---------------------------------------------------------------------------
__global__ __launch_bounds__(256)
void decomp_add(float* __restrict__ h, const float* __restrict__ a) {
  int idx = blockIdx.x * blockDim.x + threadIdx.x;
  if (idx >= BB * DD) return;
  int b = idx >> 7, d = idx & 127;
  float* hb = h + (size_t)b * LL * DD + d;
  const float* ab = a + (size_t)b * LL * DD + d;
  float x[LL];
#pragma unroll
  for (int t = 0; t < LL; t++) x[t] = hb[t * DD] + ab[t * DD];
  float s = 13.0f * x[0];
#pragma unroll
  for (int u = 1; u <= 12; u++) s += x[u];
#pragma unroll
  for (int t = 0; t < LL; t++) {
    hb[t * DD] = x[t] - s * (1.0f / 25.0f);
    int add = (t + 13 > LL - 1) ? (LL - 1) : (t + 13);
    int sub = (t - 12 < 0) ? 0 : (t - 12);
    s += x[add] - x[sub];
  }
}

// ---------------------------------------------------------------------------
// my_Layernorm: LN over D, then subtract per-(b,d) time mean. Block per b.
// ---------------------------------------------------------------------------
__global__ __launch_bounds__(256)
void ln_kernel(const float* __restrict__ h, const float* __restrict__ lw,
               const float* __restrict__ lb, float* __restrict__ out) {
  const int b = blockIdx.x;
  __shared__ float xs[LL][129];
  const int tid = threadIdx.x;
  const int wave = tid >> 6, lane = tid & 63;
  const float* hb = h + (size_t)b * LL * DD;
  for (int t = wave; t < LL; t += 4) {
    float a0 = hb[t * DD + lane], a1 = hb[t * DD + 64 + lane];
    float s = a0 + a1, ss = a0 * a0 + a1 * a1;
#pragma unroll
    for (int off = 32; off >= 1; off >>= 1) {
      s  += __shfl_down(s, off);
      ss += __shfl_down(ss, off);
    }
    s = __shfl(s, 0); ss = __shfl(ss, 0);
    float mu = s * (1.0f / 128.0f);
    float var = ss * (1.0f / 128.0f) - mu * mu;
    float inv = rsqrtf(var + 1e-5f);
    xs[t][lane]      = (a0 - mu) * inv * lw[lane]      + lb[lane];
    xs[t][64 + lane] = (a1 - mu) * inv * lw[64 + lane] + lb[64 + lane];
  }
  __syncthreads();
  if (tid < DD) {
    float cs = 0.f;
#pragma unroll
    for (int t = 0; t < LL; t++) cs += xs[t][tid];
    cs *= (1.0f / 36.0f);
    float* ob = out + (size_t)b * LL * DD;
#pragma unroll
    for (int t = 0; t < LL; t++) ob[t * DD + tid] = xs[t][tid] - cs;
  }
}

// ---------------------------------------------------------------------------
// fc3 ([4608]->[2]) + softmax. Block per batch row.
// ---------------------------------------------------------------------------
__global__ __launch_bounds__(256)
void fc3_softmax(const float* __restrict__ z, const float* __restrict__ w,
                 const float* __restrict__ bias, float* __restrict__ out) {
  const int b = blockIdx.x;
  const int tid = threadIdx.x;
  const float* zb = z + (size_t)b * (LL * DD);
  float s0 = 0.f, s1 = 0.f;
  for (int i = tid; i < LL * DD; i += 256) {
    float x = zb[i];
    s0 += x * w[i * 2];
    s1 += x * w[i * 2 + 1];
  }
  __shared__ float r0[4], r1[4];
#pragma unroll
  for (int off = 32; off >= 1; off >>= 1) {
    s0 += __shfl_down(s0, off);
    s1 += __shfl_down(s1, off);
  }
  int wave = tid >> 6, lane = tid & 63;
  if (lane == 0) { r0[wave] = s0; r1[wave] = s1; }
  __syncthreads();
  if (tid == 0) {
    float a = r0[0] + r0[1] + r0[2] + r0[3] + bias[0];
    float c = r1[0] + r1[1] + r1[2] + r1[3] + bias[1];
    float m = fmaxf(a, c);
    float ea = expf(a - m), ec = expf(c - m);
    float inv = 1.0f / (ea + ec);
    out[(size_t)b * 2]     = ea * inv;
    out[(size_t)b * 2 + 1] = ec * inv;
  }
}

// ---------------------------------------------------------------------------
extern "C" void kernel_launch(void* const* d_in, const int* in_sizes, int n_in,
                              void* d_out, int out_size, void* d_ws, size_t ws_size,
                              hipStream_t stream) {
  const float* x        = (const float*)d_in[0];
  const float* linear_w = (const float*)d_in[1];
  const float* linear_b = (const float*)d_in[2];
  const float* Wq = (const float*)d_in[3];
  const float* bq = (const float*)d_in[4];
  const float* Wk = (const float*)d_in[5];
  const float* bk = (const float*)d_in[6];
  const float* Wv = (const float*)d_in[7];
  const float* bv = (const float*)d_in[8];
  const float* Wo = (const float*)d_in[9];
  const float* bo = (const float*)d_in[10];
  const float* conv1_w = (const float*)d_in[11];
  const float* conv2_w = (const float*)d_in[12];
  const float* ln_w = (const float*)d_in[13];
  const float* ln_b = (const float*)d_in[14];
  const float* fc1_w = (const float*)d_in[15];
  const float* fc1_b = (const float*)d_in[16];
  const float* fc2_w = (const float*)d_in[17];
  const float* fc2_b = (const float*)d_in[18];
  const float* fc3_w = (const float*)d_in[19];
  const float* fc3_b = (const float*)d_in[20];
  float* out = (float*)d_out;

  // Workspace layout (floats): h | q | k | mid(4S). v aliases mid's head.
  // agg aliases q (safe), per-layer 'a'/'y' go into k. Total 7S = ~528 MB.
  float* ws  = (float*)d_ws;
  float* h   = ws;
  float* q   = h + SFL;
  float* k   = q + SFL;
  float* mid = k + SFL;
  float* v   = mid;

  dim3 blk(256);

  // h = x @ linear_w + linear_b   [4096,36]x[36,4608]
  gemm_f32<0><<<dim3(4608 / 64, BB / 64), blk, 0, stream>>>(
      x, linear_w, linear_b, h, BB, 4608, 36);

  for (int i = 0; i < ELAYERS; i++) {
    const float* wq = Wq + (size_t)i * DD * DD;
    const float* wk = Wk + (size_t)i * DD * DD;
    const float* wv = Wv + (size_t)i * DD * DD;
    const float* wo = Wo + (size_t)i * DD * DD;
    const float* c1 = conv1_w + (size_t)i * DD * DFF;
    const float* c2 = conv2_w + (size_t)i * DFF * DD;

    gemm_f32<0><<<dim3(2, MROW / 64), blk, 0, stream>>>(h, wq, bq + i * DD, q, MROW, DD, DD);
    gemm_f32<0><<<dim3(2, MROW / 64), blk, 0, stream>>>(h, wk, bk + i * DD, k, MROW, DD, DD);
    gemm_f32<0><<<dim3(2, MROW / 64), blk, 0, stream>>>(h, wv, bv + i * DD, v, MROW, DD, DD);

    autocorr_kernel<<<BB, blk, 0, stream>>>(q, k, v, q);  // agg -> q

    gemm_f32<0><<<dim3(2, MROW / 64), blk, 0, stream>>>(q, wo, bo + i * DD, k, MROW, DD, DD);
    decomp_add<<<(BB * DD) / 256, blk, 0, stream>>>(h, k);  // h = (h+a) - MA

    gemm_f32<1><<<dim3(DFF / 64, MROW / 64), blk, 0, stream>>>(h, c1, nullptr, mid, MROW, DFF, DD);
    gemm_f32<0><<<dim3(2, MROW / 64), blk, 0, stream>>>(mid, c2, nullptr, k, MROW, DD, DFF);
    decomp_add<<<(BB * DD) / 256, blk, 0, stream>>>(h, k);  // h = (h+y) - MA
  }

  // Final LN (+ time-mean subtract) -> flat in q
  ln_kernel<<<BB, blk, 0, stream>>>(h, ln_w, ln_b, q);

  // fc1 (gelu) -> mid ; fc2 -> k ; fc3+softmax -> out
  gemm_f32<1><<<dim3(13824 / 64, BB / 64), blk, 0, stream>>>(q, fc1_w, fc1_b, mid, BB, 13824, 4608);
  gemm_f32<0><<<dim3(4608 / 64, BB / 64), blk, 0, stream>>>(mid, fc2_w, fc2_b, k, BB, 4608, 13824);
  fc3_softmax<<<BB, blk, 0, stream>>>(k, fc3_w, fc3_b, out);
}

// Round 2
// 11748.909 us; speedup vs baseline: 2.6988x; 2.6988x over previous
//
#include <hip/hip_runtime.h>
#include <hip/hip_bf16.h>

#define BB   4096
#define LL   36
#define DD   128
#define DFF  512
#define ELAYERS 8
#define MROW (BB*LL)             // 147456
#define SFL  ((size_t)BB*LL*DD)  // 18874368 elements per [B,L,D] buffer

typedef __attribute__((ext_vector_type(8))) short short8;
typedef __attribute__((ext_vector_type(4))) float f32x4;
typedef __hip_bfloat16 bf16;

__device__ __forceinline__ float gelu_exact(float x) {
  return 0.5f * x * (1.0f + erff(x * 0.70710678118654752f));
}

__device__ __forceinline__ void split_val(float v, bf16* hi, bf16* lo) {
  bf16 h = __float2bfloat16(v);
  *hi = h;
  *lo = __float2bfloat16(v - __bfloat162float(h));
}

__device__ __forceinline__ void async16(const void* g, void* l) {
  __builtin_amdgcn_global_load_lds(
      (const __attribute__((address_space(1))) void*)g,
      (__attribute__((address_space(3))) void*)l, 16, 0, 0);
}

// ---------------------------------------------------------------------------
// fp32 GEMM (kept for linear embed + q/k projections): C = A@B + bias
// ---------------------------------------------------------------------------
template<int ACT>
__global__ __launch_bounds__(256)
void gemm_f32(const float* __restrict__ A, const float* __restrict__ B,
              const float* __restrict__ bias, float* __restrict__ C,
              int M, int N, int K) {
  __shared__ float As[16][68];
  __shared__ float Bs[16][68];
  const int bm = blockIdx.y * 64, bn = blockIdx.x * 64;
  const int tid = threadIdx.x;
  const int tr = tid >> 4, tc = tid & 15;
  float acc[4][4] = {};
  for (int k0 = 0; k0 < K; k0 += 16) {
#pragma unroll
    for (int i = 0; i < 4; i++) {
      int idx = tid + i * 256;
      int m = idx >> 4, kk = idx & 15;
      float va = 0.f;
      if (bm + m < M && k0 + kk < K) va = A[(size_t)(bm + m) * K + k0 + kk];
      As[kk][m] = va;
      int kk2 = idx >> 6, n = idx & 63;
      float vb = 0.f;
      if (k0 + kk2 < K && bn + n < N) vb = B[(size_t)(k0 + kk2) * N + bn + n];
      Bs[kk2][n] = vb;
    }
    __syncthreads();
#pragma unroll
    for (int kk = 0; kk < 16; kk++) {
      const float4 av = *(const float4*)&As[kk][tr * 4];
      const float4 bv = *(const float4*)&Bs[kk][tc * 4];
      const float a4[4] = {av.x, av.y, av.z, av.w};
      const float b4[4] = {bv.x, bv.y, bv.z, bv.w};
#pragma unroll
      for (int i = 0; i < 4; i++)
#pragma unroll
        for (int j = 0; j < 4; j++)
          acc[i][j] += a4[i] * b4[j];
    }
    __syncthreads();
  }
#pragma unroll
  for (int i = 0; i < 4; i++) {
    int m = bm + tr * 4 + i;
    if (m >= M) continue;
#pragma unroll
    for (int j = 0; j < 4; j++) {
      int n = bn + tc * 4 + j;
      if (n >= N) continue;
      float v = acc[i][j];
      if (bias) v += bias[n];
      if (ACT == 1) v = gelu_exact(v);
      C[(size_t)m * N + n] = v;
    }
  }
}

// ---------------------------------------------------------------------------
// Split-bf16 MFMA GEMM: C[M,N] = act(A@W + bias) with A = Ah+Al (bf16 planes,
// [M,K] lda), W^T = Bh+Bl ([N,K] ldb). 3 MFMAs per tile: hh + hl + lh.
// 128x128 tile, BK=32, 256 threads, global_load_lds staging.
// OUT_SPLIT: 0 -> fp32 Cf; 1 -> split planes Ch/Cl. ACC: Cf += (OUT_SPLIT=0).
// Requires M%128==0, N%128==0, K%32==0.
// ---------------------------------------------------------------------------
template<int ACT, int OUT_SPLIT, int ACC>
__global__ __launch_bounds__(256)
void gemm_split(const bf16* __restrict__ Ah, const bf16* __restrict__ Al,
                const bf16* __restrict__ Bh, const bf16* __restrict__ Bl,
                const float* __restrict__ bias,
                float* __restrict__ Cf, bf16* __restrict__ Ch, bf16* __restrict__ Cl,
                int M, int N, int K, int lda, int ldb) {
  __shared__ short Ah_s[4096];
  __shared__ short Al_s[4096];
  __shared__ short Bh_s[4096];
  __shared__ short Bl_s[4096];
  const int tid = threadIdx.x;
  const int wave = tid >> 6, lane = tid & 63;
  const int bm = blockIdx.y * 128, bn = blockIdx.x * 128;
  const int wr = wave >> 1, wc = wave & 1;

  // staging: chunk c covers tile rows c*16..c*16+15; wave handles chunks wave, wave+4
  const int srow = wave * 16 + (lane >> 2);
  const int scol = (lane & 3) * 8;
  const size_t a0 = (size_t)(bm + srow) * lda + scol;
  const size_t a1 = (size_t)(bm + srow + 64) * lda + scol;
  const size_t b0 = (size_t)(bn + srow) * ldb + scol;
  const size_t b1 = (size_t)(bn + srow + 64) * ldb + scol;
  const int l0 = wave * 512;        // LDS chunk base (elems); lane adds lane*8
  const int l1 = (wave + 4) * 512;

  f32x4 acc[4][4];
#pragma unroll
  for (int i = 0; i < 4; i++)
#pragma unroll
    for (int j = 0; j < 4; j++) acc[i][j] = (f32x4)0.0f;

  const int fr = lane & 15;
  const int fk = (lane >> 4) * 8;

  for (int k0 = 0; k0 < K; k0 += 32) {
    async16(Ah + a0 + k0, &Ah_s[l0]);
    async16(Ah + a1 + k0, &Ah_s[l1]);
    async16(Al + a0 + k0, &Al_s[l0]);
    async16(Al + a1 + k0, &Al_s[l1]);
    async16(Bh + b0 + k0, &Bh_s[l0]);
    async16(Bh + b1 + k0, &Bh_s[l1]);
    async16(Bl + b0 + k0, &Bl_s[l0]);
    async16(Bl + b1 + k0, &Bl_s[l1]);
    __syncthreads();
    short8 ah[4], al[4], bh[4], bl[4];
#pragma unroll
    for (int mi = 0; mi < 4; mi++) {
      int off = (wr * 64 + mi * 16 + fr) * 32 + fk;
      ah[mi] = *(const short8*)&Ah_s[off];
      al[mi] = *(const short8*)&Al_s[off];
    }
#pragma unroll
    for (int ni = 0; ni < 4; ni++) {
      int off = (wc * 64 + ni * 16 + fr) * 32 + fk;
      bh[ni] = *(const short8*)&Bh_s[off];
      bl[ni] = *(const short8*)&Bl_s[off];
    }
#pragma unroll
    for (int mi = 0; mi < 4; mi++)
#pragma unroll
      for (int ni = 0; ni < 4; ni++) {
        acc[mi][ni] = __builtin_amdgcn_mfma_f32_16x16x32_bf16(ah[mi], bh[ni], acc[mi][ni], 0, 0, 0);
        acc[mi][ni] = __builtin_amdgcn_mfma_f32_16x16x32_bf16(ah[mi], bl[ni], acc[mi][ni], 0, 0, 0);
        acc[mi][ni] = __builtin_amdgcn_mfma_f32_16x16x32_bf16(al[mi], bh[ni], acc[mi][ni], 0, 0, 0);
      }
    __syncthreads();
  }

  const int er = (lane >> 4) * 4;
  const int ec = lane & 15;
#pragma unroll
  for (int mi = 0; mi < 4; mi++) {
#pragma unroll
    for (int r = 0; r < 4; r++) {
      size_t row = bm + wr * 64 + mi * 16 + er + r;
#pragma unroll
      for (int ni = 0; ni < 4; ni++) {
        int col = bn + wc * 64 + ni * 16 + ec;
        float v = acc[mi][ni][r];
        size_t idx = row * (size_t)N + col;
        if (ACC) v += Cf[idx];
        if (bias) v += bias[col];
        if (ACT == 1) v = gelu_exact(v);
        if (OUT_SPLIT) {
          bf16 hi, lo; split_val(v, &hi, &lo);
          Ch[idx] = hi; Cl[idx] = lo;
        } else {
          Cf[idx] = v;
        }
      }
    }
  }
}

// ---------------------------------------------------------------------------
// Transpose + split-cast: in [K,N] fp32 (ldin) -> out planes [N,K] bf16.
// Grid (N/32, K/32, batch), block 256.
// ---------------------------------------------------------------------------
__global__ __launch_bounds__(256)
void transpose_split(const float* __restrict__ in, bf16* __restrict__ oh,
                     bf16* __restrict__ ol, int K, int N, int ldin,
                     size_t in_bstride, size_t out_bstride) {
  __shared__ float t[32][33];
  const int n0 = blockIdx.x * 32, k0 = blockIdx.y * 32;
  in += (size_t)blockIdx.z * in_bstride;
  oh += (size_t)blockIdx.z * out_bstride;
  ol += (size_t)blockIdx.z * out_bstride;
  const int tx = threadIdx.x & 31, ty = threadIdx.x >> 5;
#pragma unroll
  for (int j = 0; j < 4; j++)
    t[ty + j * 8][tx] = in[(size_t)(k0 + ty + j * 8) * ldin + n0 + tx];
  __syncthreads();
#pragma unroll
  for (int j = 0; j < 4; j++) {
    float v = t[tx][ty + j * 8];
    bf16 hi, lo; split_val(v, &hi, &lo);
    size_t idx = (size_t)(n0 + ty + j * 8) * K + k0 + tx;
    oh[idx] = hi; ol[idx] = lo;
  }
}

// Elementwise split-cast
__global__ __launch_bounds__(256)
void split_cast(const float* __restrict__ in, bf16* __restrict__ oh,
                bf16* __restrict__ ol, size_t n) {
  size_t i = (size_t)blockIdx.x * 256 + threadIdx.x;
  if (i >= n) return;
  bf16 hi, lo; split_val(in[i], &hi, &lo);
  oh[i] = hi; ol[i] = lo;
}

// ---------------------------------------------------------------------------
// Autocorrelation: corr from fp32 q,k; top-3 delays; agg(v) -> split planes
// ---------------------------------------------------------------------------
__global__ __launch_bounds__(256)
void autocorr_kernel(const float* __restrict__ q, const float* __restrict__ k,
                     const float* __restrict__ v,
                     bf16* __restrict__ ah_, bf16* __restrict__ al_) {
  const int b = blockIdx.x;
  const float* qb = q + (size_t)b * LL * DD;
  const float* kb = k + (size_t)b * LL * DD;
  const float* vb = v + (size_t)b * LL * DD;
  __shared__ float qs[LL][129];
  __shared__ float ks[LL][129];
  __shared__ float G[LL][37];
  __shared__ float mv[LL];
  __shared__ float wts[3];
  __shared__ int   dly[3];
  const int tid = threadIdx.x;

  for (int p = tid; p < LL * DD; p += 256) {
    int t = p >> 7, d = p & 127;
    qs[t][d] = qb[p];
    ks[t][d] = kb[p];
  }
  __syncthreads();

  for (int p = tid; p < LL * LL; p += 256) {
    int s2 = p / LL, s = p % LL;
    float acc = 0.f;
#pragma unroll 8
    for (int d = 0; d < DD; d++) acc += qs[s2][d] * ks[s][d];
    G[s2][s] = acc;
  }
  __syncthreads();

  if (tid < LL) {
    float acc = 0.f;
    for (int s = 0; s < LL; s++) acc += G[(s + tid) % LL][s];
    mv[tid] = acc * (1.0f / 128.0f);
  }
  __syncthreads();

  if (tid == 0) {
    int d0 = -1, d1 = -1, d2 = -1;
    float v0 = -1e30f, v1 = -1e30f, v2 = -1e30f;
    for (int t = 0; t < LL; t++) {
      float x = mv[t];
      if (x > v0)      { v2 = v1; d2 = d1; v1 = v0; d1 = d0; v0 = x; d0 = t; }
      else if (x > v1) { v2 = v1; d2 = d1; v1 = x;  d1 = t; }
      else if (x > v2) { v2 = x;  d2 = t; }
    }
    float e1 = expf(v1 - v0), e2 = expf(v2 - v0);
    float inv = 1.0f / (1.0f + e1 + e2);
    wts[0] = inv; wts[1] = e1 * inv; wts[2] = e2 * inv;
    dly[0] = d0; dly[1] = d1; dly[2] = d2;
  }
  __syncthreads();

  const float w0 = wts[0], w1 = wts[1], w2 = wts[2];
  const int  e0 = dly[0], e1 = dly[1], e2 = dly[2];
  bf16* ahb = ah_ + (size_t)b * LL * DD;
  bf16* alb = al_ + (size_t)b * LL * DD;
  for (int p = tid; p < LL * DD; p += 256) {
    int t = p >> 7, d = p & 127;
    float r = w0 * vb[((t + e0) % LL) * DD + d]
            + w1 * vb[((t + e1) % LL) * DD + d]
            + w2 * vb[((t + e2) % LL) * DD + d];
    bf16 hi, lo; split_val(r, &hi, &lo);
    ahb[p] = hi; alb[p] = lo;
  }
}

// ---------------------------------------------------------------------------
// h = (h+a) - movavg25(h+a); writes fp32 h AND split planes of h
// ---------------------------------------------------------------------------
__global__ __launch_bounds__(256)
void decomp_add(float* __restrict__ h, const float* __restrict__ a,
                bf16* __restrict__ hh, bf16* __restrict__ hl) {
  int idx = blockIdx.x * blockDim.x + threadIdx.x;
  if (idx >= BB * DD) return;
  int b = idx >> 7, d = idx & 127;
  size_t base = (size_t)b * LL * DD + d;
  float* hb = h + base;
  const float* ab = a + base;
  float x[LL];
#pragma unroll
  for (int t = 0; t < LL; t++) x[t] = hb[t * DD] + ab[t * DD];
  float s = 13.0f * x[0];
#pragma unroll
  for (int u = 1; u <= 12; u++) s += x[u];
#pragma unroll
  for (int t = 0; t < LL; t++) {
    float val = x[t] - s * (1.0f / 25.0f);
    hb[t * DD] = val;
    bf16 hi, lo; split_val(val, &hi, &lo);
    hh[base + t * DD] = hi;
    hl[base + t * DD] = lo;
    int add = (t + 13 > LL - 1) ? (LL - 1) : (t + 13);
    int sub = (t - 12 < 0) ? 0 : (t - 12);
    s += x[add] - x[sub];
  }
}

// ---------------------------------------------------------------------------
// my_Layernorm -> split planes output
// ---------------------------------------------------------------------------
__global__ __launch_bounds__(256)
void ln_kernel(const float* __restrict__ h, const float* __restrict__ lw,
               const float* __restrict__ lb, bf16* __restrict__ oh,
               bf16* __restrict__ ol) {
  const int b = blockIdx.x;
  __shared__ float xs[LL][129];
  const int tid = threadIdx.x;
  const int wave = tid >> 6, lane = tid & 63;
  const float* hb = h + (size_t)b * LL * DD;
  for (int t = wave; t < LL; t += 4) {
    float a0 = hb[t * DD + lane], a1 = hb[t * DD + 64 + lane];
    float s = a0 + a1, ss = a0 * a0 + a1 * a1;
#pragma unroll
    for (int off = 32; off >= 1; off >>= 1) {
      s  += __shfl_down(s, off);
      ss += __shfl_down(ss, off);
    }
    s = __shfl(s, 0); ss = __shfl(ss, 0);
    float mu = s * (1.0f / 128.0f);
    float var = ss * (1.0f / 128.0f) - mu * mu;
    float inv = rsqrtf(var + 1e-5f);
    xs[t][lane]      = (a0 - mu) * inv * lw[lane]      + lb[lane];
    xs[t][64 + lane] = (a1 - mu) * inv * lw[64 + lane] + lb[64 + lane];
  }
  __syncthreads();
  if (tid < DD) {
    float cs = 0.f;
#pragma unroll
    for (int t = 0; t < LL; t++) cs += xs[t][tid];
    cs *= (1.0f / 36.0f);
    size_t base = (size_t)b * LL * DD;
#pragma unroll
    for (int t = 0; t < LL; t++) {
      float v = xs[t][tid] - cs;
      bf16 hi, lo; split_val(v, &hi, &lo);
      oh[base + t * DD + tid] = hi;
      ol[base + t * DD + tid] = lo;
    }
  }
}

// ---------------------------------------------------------------------------
__global__ __launch_bounds__(256)
void fc3_softmax(const float* __restrict__ z, const float* __restrict__ w,
                 const float* __restrict__ bias, float* __restrict__ out) {
  const int b = blockIdx.x;
  const int tid = threadIdx.x;
  const float* zb = z + (size_t)b * (LL * DD);
  float s0 = 0.f, s1 = 0.f;
  for (int i = tid; i < LL * DD; i += 256) {
    float x = zb[i];
    s0 += x * w[i * 2];
    s1 += x * w[i * 2 + 1];
  }
  __shared__ float r0[4], r1[4];
#pragma unroll
  for (int off = 32; off >= 1; off >>= 1) {
    s0 += __shfl_down(s0, off);
    s1 += __shfl_down(s1, off);
  }
  int wave = tid >> 6, lane = tid & 63;
  if (lane == 0) { r0[wave] = s0; r1[wave] = s1; }
  __syncthreads();
  if (tid == 0) {
    float a = r0[0] + r0[1] + r0[2] + r0[3] + bias[0];
    float c = r1[0] + r1[1] + r1[2] + r1[3] + bias[1];
    float m = fmaxf(a, c);
    float ea = expf(a - m), ec = expf(c - m);
    float inv = 1.0f / (ea + ec);
    out[(size_t)b * 2]     = ea * inv;
    out[(size_t)b * 2 + 1] = ec * inv;
  }
}

// ---------------------------------------------------------------------------
extern "C" void kernel_launch(void* const* d_in, const int* in_sizes, int n_in,
                              void* d_out, int out_size, void* d_ws, size_t ws_size,
                              hipStream_t stream) {
  const float* x        = (const float*)d_in[0];
  const float* linear_w = (const float*)d_in[1];
  const float* linear_b = (const float*)d_in[2];
  const float* Wq = (const float*)d_in[3];
  const float* bq = (const float*)d_in[4];
  const float* Wk = (const float*)d_in[5];
  const float* bk = (const float*)d_in[6];
  const float* Wv = (const float*)d_in[7];
  const float* bv = (const float*)d_in[8];
  const float* Wo = (const float*)d_in[9];
  const float* bo = (const float*)d_in[10];
  const float* conv1_w = (const float*)d_in[11];
  const float* conv2_w = (const float*)d_in[12];
  const float* ln_w = (const float*)d_in[13];
  const float* ln_b = (const float*)d_in[14];
  const float* fc1_w = (const float*)d_in[15];
  const float* fc1_b = (const float*)d_in[16];
  const float* fc2_w = (const float*)d_in[17];
  const float* fc2_b = (const float*)d_in[18];
  const float* fc3_w = (const float*)d_in[19];
  const float* fc3_b = (const float*)d_in[20];
  float* out = (float*)d_out;

  // Workspace layout (bytes):
  // h: SFL*4 | hb planes: SFL*4 | q: SFL*4 | k: SFL*4 | agg planes: SFL*4 |
  // midreg: SFL*8 (v fp32 early, mid-half planes later) | small weightsT
  char* base = (char*)d_ws;
  float* h      = (float*)base;
  bf16* hb_hi   = (bf16*)(base + SFL * 4);
  bf16* hb_lo   = hb_hi + SFL;
  float* q      = (float*)(base + SFL * 8);
  float* kbuf   = (float*)(base + SFL * 12);
  bf16* agg_hi  = (bf16*)(base + SFL * 16);
  bf16* agg_lo  = agg_hi + SFL;
  char* midreg  = base + SFL * 20;
  float* v      = (float*)midreg;
  bf16* mid_hi  = (bf16*)midreg;          // [MROW,256] per half
  bf16* mid_lo  = mid_hi + 2 * SFL;
  bf16* wvT_hi  = (bf16*)(base + SFL * 28);
  bf16* wvT_lo  = wvT_hi + 8 * 16384;
  bf16* woT_hi  = wvT_lo + 8 * 16384;
  bf16* woT_lo  = woT_hi + 8 * 16384;
  bf16* c1T_hi  = woT_lo + 8 * 16384;
  bf16* c1T_lo  = c1T_hi + 8 * 65536;
  bf16* c2T_hi  = c1T_lo + 8 * 65536;
  bf16* c2T_lo  = c2T_hi + 8 * 65536;
  // endgame pool reuses q..midreg (SFL*20 bytes)
  bf16* fc1T_hi = (bf16*)q;
  bf16* fc1T_lo = fc1T_hi + (size_t)6912 * 4608;
  bf16* z1_hi   = fc1T_lo + (size_t)6912 * 4608;
  bf16* z1_lo   = z1_hi + (size_t)4096 * 6912;
  bf16* fc2T_hi = z1_lo + (size_t)4096 * 6912;
  bf16* fc2T_lo = fc2T_hi + (size_t)4608 * 6912;
  float* z2     = h;   // h is free after ln

  dim3 blk(256);

  // Embed: h = x @ linear_w + b  (fp32, K=36)
  gemm_f32<0><<<dim3(72, 64), blk, 0, stream>>>(x, linear_w, linear_b, h, BB, 4608, 36);
  split_cast<<<dim3((unsigned)(SFL / 256)), blk, 0, stream>>>(h, hb_hi, hb_lo, SFL);

  // Pre-transpose + split weights (batched over 8 layers)
  transpose_split<<<dim3(4, 4, 8),  blk, 0, stream>>>(Wv,      wvT_hi, wvT_lo, 128, 128, 128, 16384, 16384);
  transpose_split<<<dim3(4, 4, 8),  blk, 0, stream>>>(Wo,      woT_hi, woT_lo, 128, 128, 128, 16384, 16384);
  transpose_split<<<dim3(16, 4, 8), blk, 0, stream>>>(conv1_w, c1T_hi, c1T_lo, 128, 512, 512, 65536, 65536);
  transpose_split<<<dim3(4, 16, 8), blk, 0, stream>>>(conv2_w, c2T_hi, c2T_lo, 512, 128, 128, 65536, 65536);

  for (int i = 0; i < ELAYERS; i++) {
    const size_t wo16 = (size_t)i * 16384;
    const size_t wo64 = (size_t)i * 65536;
    // q,k in fp32 (protect discrete top-k delay selection)
    gemm_f32<0><<<dim3(2, 2304), blk, 0, stream>>>(h, Wq + wo16, bq + i * DD, q,    MROW, DD, DD);
    gemm_f32<0><<<dim3(2, 2304), blk, 0, stream>>>(h, Wk + wo16, bk + i * DD, kbuf, MROW, DD, DD);
    // v via split MFMA
    gemm_split<0,0,0><<<dim3(1, 1152), blk, 0, stream>>>(
        hb_hi, hb_lo, wvT_hi + wo16, wvT_lo + wo16, bv + i * DD,
        v, nullptr, nullptr, MROW, DD, DD, DD, DD);
    autocorr_kernel<<<dim3(BB), blk, 0, stream>>>(q, kbuf, v, agg_hi, agg_lo);
    // out-proj
    gemm_split<0,0,0><<<dim3(1, 1152), blk, 0, stream>>>(
        agg_hi, agg_lo, woT_hi + wo16, woT_lo + wo16, bo + i * DD,
        kbuf, nullptr, nullptr, MROW, DD, DD, DD, DD);
    decomp_add<<<dim3((BB * DD) / 256), blk, 0, stream>>>(h, kbuf, hb_hi, hb_lo);
    // FFN in two N/K halves (mid half = [MROW,256])
    for (int half = 0; half < 2; half++) {
      gemm_split<1,1,0><<<dim3(2, 1152), blk, 0, stream>>>(
          hb_hi, hb_lo, c1T_hi + wo64 + half * 32768, c1T_lo + wo64 + half * 32768, nullptr,
          nullptr, mid_hi, mid_lo, MROW, 256, DD, DD, DD);
      if (half == 0)
        gemm_split<0,0,0><<<dim3(1, 1152), blk, 0, stream>>>(
            mid_hi, mid_lo, c2T_hi + wo64, c2T_lo + wo64, nullptr,
            kbuf, nullptr, nullptr, MROW, DD, 256, 256, DFF);
      else
        gemm_split<0,0,1><<<dim3(1, 1152), blk, 0, stream>>>(
            mid_hi, mid_lo, c2T_hi + wo64 + 256, c2T_lo + wo64 + 256, nullptr,
            kbuf, nullptr, nullptr, MROW, DD, 256, 256, DFF);
    }
    decomp_add<<<dim3((BB * DD) / 256), blk, 0, stream>>>(h, kbuf, hb_hi, hb_lo);
  }

  // LN -> flat split planes (into hb)
  ln_kernel<<<dim3(BB), blk, 0, stream>>>(h, ln_w, ln_b, hb_hi, hb_lo);

  // Head: fc1 (gelu) + fc2, chunked in halves of the 13824 dim
  for (int half = 0; half < 2; half++) {
    transpose_split<<<dim3(216, 144, 1), blk, 0, stream>>>(
        fc1_w + half * 6912, fc1T_hi, fc1T_lo, 4608, 6912, 13824, 0, 0);
    gemm_split<1,1,0><<<dim3(54, 32), blk, 0, stream>>>(
        hb_hi, hb_lo, fc1T_hi, fc1T_lo, fc1_b + half * 6912,
        nullptr, z1_hi, z1_lo, BB, 6912, 4608, 4608, 4608);
    transpose_split<<<dim3(144, 216, 1), blk, 0, stream>>>(
        fc2_w + (size_t)half * 6912 * 4608, fc2T_hi, fc2T_lo, 6912, 4608, 4608, 0, 0);
    if (half == 0)
      gemm_split<0,0,0><<<dim3(36, 32), blk, 0, stream>>>(
          z1_hi, z1_lo, fc2T_hi, fc2T_lo, fc2_b,
          z2, nullptr, nullptr, BB, 4608, 6912, 6912, 6912);
    else
      gemm_split<0,0,1><<<dim3(36, 32), blk, 0, stream>>>(
          z1_hi, z1_lo, fc2T_hi, fc2T_lo, nullptr,
          z2, nullptr, nullptr, BB, 4608, 6912, 6912, 6912);
  }
  fc3_softmax<<<dim3(BB), blk, 0, stream>>>(z2, fc3_w, fc3_b, out);
}

// Round 3
// 8101.537 us; speedup vs baseline: 3.9139x; 1.4502x over previous
//
#include <hip/hip_runtime.h>
#include <hip/hip_bf16.h>

#define BB   4096
#define LL   36
#define DD   128
#define DFF  512
#define ELAYERS 8
#define MROW (BB*LL)             // 147456
#define SFL  ((size_t)BB*LL*DD)  // 18874368 elements per [B,L,D] buffer

typedef __attribute__((ext_vector_type(8))) short short8;
typedef __attribute__((ext_vector_type(4))) float f32x4;
typedef __hip_bfloat16 bf16;

__device__ __forceinline__ float gelu_exact(float x) {
  return 0.5f * x * (1.0f + erff(x * 0.70710678118654752f));
}

__device__ __forceinline__ void split_val(float v, bf16* hi, bf16* lo) {
  bf16 h = __float2bfloat16(v);
  *hi = h;
  *lo = __float2bfloat16(v - __bfloat162float(h));
}

__device__ __forceinline__ void async16(const void* g, void* l) {
  __builtin_amdgcn_global_load_lds(
      (const __attribute__((address_space(1))) void*)g,
      (__attribute__((address_space(3))) void*)l, 16, 0, 0);
}

// ---------------------------------------------------------------------------
// fp32 GEMM (embed only): C = A@B + bias
// ---------------------------------------------------------------------------
template<int ACT>
__global__ __launch_bounds__(256)
void gemm_f32(const float* __restrict__ A, const float* __restrict__ B,
              const float* __restrict__ bias, float* __restrict__ C,
              int M, int N, int K) {
  __shared__ float As[16][68];
  __shared__ float Bs[16][68];
  const int bm = blockIdx.y * 64, bn = blockIdx.x * 64;
  const int tid = threadIdx.x;
  const int tr = tid >> 4, tc = tid & 15;
  float acc[4][4] = {};
  for (int k0 = 0; k0 < K; k0 += 16) {
#pragma unroll
    for (int i = 0; i < 4; i++) {
      int idx = tid + i * 256;
      int m = idx >> 4, kk = idx & 15;
      float va = 0.f;
      if (bm + m < M && k0 + kk < K) va = A[(size_t)(bm + m) * K + k0 + kk];
      As[kk][m] = va;
      int kk2 = idx >> 6, n = idx & 63;
      float vb = 0.f;
      if (k0 + kk2 < K && bn + n < N) vb = B[(size_t)(k0 + kk2) * N + bn + n];
      Bs[kk2][n] = vb;
    }
    __syncthreads();
#pragma unroll
    for (int kk = 0; kk < 16; kk++) {
      const float4 av = *(const float4*)&As[kk][tr * 4];
      const float4 bv = *(const float4*)&Bs[kk][tc * 4];
      const float a4[4] = {av.x, av.y, av.z, av.w};
      const float b4[4] = {bv.x, bv.y, bv.z, bv.w};
#pragma unroll
      for (int i = 0; i < 4; i++)
#pragma unroll
        for (int j = 0; j < 4; j++)
          acc[i][j] += a4[i] * b4[j];
    }
    __syncthreads();
  }
#pragma unroll
  for (int i = 0; i < 4; i++) {
    int m = bm + tr * 4 + i;
    if (m >= M) continue;
#pragma unroll
    for (int j = 0; j < 4; j++) {
      int n = bn + tc * 4 + j;
      if (n >= N) continue;
      float v = acc[i][j];
      if (bias) v += bias[n];
      if (ACT == 1) v = gelu_exact(v);
      C[(size_t)m * N + n] = v;
    }
  }
}

// ---------------------------------------------------------------------------
// Split-bf16 MFMA GEMM: C[M,N] = act(A@W + bias), A = Ah+Al ([M,K] lda),
// W^T = Bh+Bl ([N,K] ldb). 3 MFMAs: hh + hl + lh (error ~2^-17).
// 128x128 tile, BK=32, 256 threads, global_load_lds staging.
// OUT_SPLIT: 0 -> fp32 Cf; 1 -> split planes Ch/Cl.
// Requires M%128==0, N%128==0, K%32==0.
// ---------------------------------------------------------------------------
template<int ACT, int OUT_SPLIT>
__global__ __launch_bounds__(256)
void gemm_split(const bf16* __restrict__ Ah, const bf16* __restrict__ Al,
                const bf16* __restrict__ Bh, const bf16* __restrict__ Bl,
                const float* __restrict__ bias,
                float* __restrict__ Cf, bf16* __restrict__ Ch, bf16* __restrict__ Cl,
                int M, int N, int K, int lda, int ldb) {
  __shared__ short Ah_s[4096];
  __shared__ short Al_s[4096];
  __shared__ short Bh_s[4096];
  __shared__ short Bl_s[4096];
  const int tid = threadIdx.x;
  const int wave = tid >> 6, lane = tid & 63;
  const int bm = blockIdx.y * 128, bn = blockIdx.x * 128;
  const int wr = wave >> 1, wc = wave & 1;

  const int srow = wave * 16 + (lane >> 2);
  const int scol = (lane & 3) * 8;
  const size_t a0 = (size_t)(bm + srow) * lda + scol;
  const size_t a1 = (size_t)(bm + srow + 64) * lda + scol;
  const size_t b0 = (size_t)(bn + srow) * ldb + scol;
  const size_t b1 = (size_t)(bn + srow + 64) * ldb + scol;
  const int l0 = wave * 512;
  const int l1 = (wave + 4) * 512;

  f32x4 acc[4][4];
#pragma unroll
  for (int i = 0; i < 4; i++)
#pragma unroll
    for (int j = 0; j < 4; j++) acc[i][j] = (f32x4)0.0f;

  const int fr = lane & 15;
  const int fk = (lane >> 4) * 8;

  for (int k0 = 0; k0 < K; k0 += 32) {
    async16(Ah + a0 + k0, &Ah_s[l0]);
    async16(Ah + a1 + k0, &Ah_s[l1]);
    async16(Al + a0 + k0, &Al_s[l0]);
    async16(Al + a1 + k0, &Al_s[l1]);
    async16(Bh + b0 + k0, &Bh_s[l0]);
    async16(Bh + b1 + k0, &Bh_s[l1]);
    async16(Bl + b0 + k0, &Bl_s[l0]);
    async16(Bl + b1 + k0, &Bl_s[l1]);
    __syncthreads();
    short8 ah[4], al[4], bh[4], bl[4];
#pragma unroll
    for (int mi = 0; mi < 4; mi++) {
      int off = (wr * 64 + mi * 16 + fr) * 32 + fk;
      ah[mi] = *(const short8*)&Ah_s[off];
      al[mi] = *(const short8*)&Al_s[off];
    }
#pragma unroll
    for (int ni = 0; ni < 4; ni++) {
      int off = (wc * 64 + ni * 16 + fr) * 32 + fk;
      bh[ni] = *(const short8*)&Bh_s[off];
      bl[ni] = *(const short8*)&Bl_s[off];
    }
#pragma unroll
    for (int mi = 0; mi < 4; mi++)
#pragma unroll
      for (int ni = 0; ni < 4; ni++) {
        acc[mi][ni] = __builtin_amdgcn_mfma_f32_16x16x32_bf16(ah[mi], bh[ni], acc[mi][ni], 0, 0, 0);
        acc[mi][ni] = __builtin_amdgcn_mfma_f32_16x16x32_bf16(ah[mi], bl[ni], acc[mi][ni], 0, 0, 0);
        acc[mi][ni] = __builtin_amdgcn_mfma_f32_16x16x32_bf16(al[mi], bh[ni], acc[mi][ni], 0, 0, 0);
      }
    __syncthreads();
  }

  const int er = (lane >> 4) * 4;
  const int ec = lane & 15;
#pragma unroll
  for (int mi = 0; mi < 4; mi++) {
#pragma unroll
    for (int r = 0; r < 4; r++) {
      size_t row = bm + wr * 64 + mi * 16 + er + r;
#pragma unroll
      for (int ni = 0; ni < 4; ni++) {
        int col = bn + wc * 64 + ni * 16 + ec;
        float v = acc[mi][ni][r];
        size_t idx = row * (size_t)N + col;
        if (bias) v += bias[col];
        if (ACT == 1) v = gelu_exact(v);
        if (OUT_SPLIT) {
          bf16 hi, lo; split_val(v, &hi, &lo);
          Ch[idx] = hi; Cl[idx] = lo;
        } else {
          Cf[idx] = v;
        }
      }
    }
  }
}

// ---------------------------------------------------------------------------
// Transpose + split-cast: in [K,N] fp32 (ldin) -> out planes [N,K] bf16.
// ---------------------------------------------------------------------------
__global__ __launch_bounds__(256)
void transpose_split(const float* __restrict__ in, bf16* __restrict__ oh,
                     bf16* __restrict__ ol, int K, int N, int ldin,
                     size_t in_bstride, size_t out_bstride) {
  __shared__ float t[32][33];
  const int n0 = blockIdx.x * 32, k0 = blockIdx.y * 32;
  in += (size_t)blockIdx.z * in_bstride;
  oh += (size_t)blockIdx.z * out_bstride;
  ol += (size_t)blockIdx.z * out_bstride;
  const int tx = threadIdx.x & 31, ty = threadIdx.x >> 5;
#pragma unroll
  for (int j = 0; j < 4; j++)
    t[ty + j * 8][tx] = in[(size_t)(k0 + ty + j * 8) * ldin + n0 + tx];
  __syncthreads();
#pragma unroll
  for (int j = 0; j < 4; j++) {
    float v = t[tx][ty + j * 8];
    bf16 hi, lo; split_val(v, &hi, &lo);
    size_t idx = (size_t)(n0 + ty + j * 8) * K + k0 + tx;
    oh[idx] = hi; ol[idx] = lo;
  }
}

__global__ __launch_bounds__(256)
void split_cast(const float* __restrict__ in, bf16* __restrict__ oh,
                bf16* __restrict__ ol, size_t n) {
  size_t i = (size_t)blockIdx.x * 256 + threadIdx.x;
  if (i >= n) return;
  bf16 hi, lo; split_val(in[i], &hi, &lo);
  oh[i] = hi; ol[i] = lo;
}

// Pack per-layer q/k biases into [8][256]
__global__ __launch_bounds__(256)
void pack_qk_bias(const float* __restrict__ bq, const float* __restrict__ bk,
                  float* __restrict__ qb) {
  int i = blockIdx.x * 256 + threadIdx.x;   // 0..2047
  int layer = i >> 8, c = i & 255;
  qb[i] = (c < 128) ? bq[layer * 128 + c] : bk[layer * 128 + (c - 128)];
}

// ---------------------------------------------------------------------------
// Autocorrelation: q,k packed [b][t][256] fp32; top-3 delays; agg(v fp32)
// -> split planes
// ---------------------------------------------------------------------------
__global__ __launch_bounds__(256)
void autocorr_kernel(const float* __restrict__ qk, const float* __restrict__ v,
                     bf16* __restrict__ ah_, bf16* __restrict__ al_) {
  const int b = blockIdx.x;
  const float* qkb = qk + (size_t)b * LL * 256;
  const float* vb = v + (size_t)b * LL * DD;
  __shared__ float qs[LL][129];
  __shared__ float ks[LL][129];
  __shared__ float G[LL][37];
  __shared__ float mv[LL];
  __shared__ float wts[3];
  __shared__ int   dly[3];
  const int tid = threadIdx.x;

  for (int p = tid; p < LL * DD; p += 256) {
    int t = p >> 7, d = p & 127;
    qs[t][d] = qkb[t * 256 + d];
    ks[t][d] = qkb[t * 256 + 128 + d];
  }
  __syncthreads();

  for (int p = tid; p < LL * LL; p += 256) {
    int s2 = p / LL, s = p % LL;
    float acc = 0.f;
#pragma unroll 8
    for (int d = 0; d < DD; d++) acc += qs[s2][d] * ks[s][d];
    G[s2][s] = acc;
  }
  __syncthreads();

  if (tid < LL) {
    float acc = 0.f;
    for (int s = 0; s < LL; s++) acc += G[(s + tid) % LL][s];
    mv[tid] = acc * (1.0f / 128.0f);
  }
  __syncthreads();

  if (tid == 0) {
    int d0 = -1, d1 = -1, d2 = -1;
    float v0 = -1e30f, v1 = -1e30f, v2 = -1e30f;
    for (int t = 0; t < LL; t++) {
      float x = mv[t];
      if (x > v0)      { v2 = v1; d2 = d1; v1 = v0; d1 = d0; v0 = x; d0 = t; }
      else if (x > v1) { v2 = v1; d2 = d1; v1 = x;  d1 = t; }
      else if (x > v2) { v2 = x;  d2 = t; }
    }
    float e1 = expf(v1 - v0), e2 = expf(v2 - v0);
    float inv = 1.0f / (1.0f + e1 + e2);
    wts[0] = inv; wts[1] = e1 * inv; wts[2] = e2 * inv;
    dly[0] = d0; dly[1] = d1; dly[2] = d2;
  }
  __syncthreads();

  const float w0 = wts[0], w1 = wts[1], w2 = wts[2];
  const int  e0 = dly[0], e1 = dly[1], e2 = dly[2];
  bf16* ahb = ah_ + (size_t)b * LL * DD;
  bf16* alb = al_ + (size_t)b * LL * DD;
  for (int p = tid; p < LL * DD; p += 256) {
    int t = p >> 7, d = p & 127;
    float r = w0 * vb[((t + e0) % LL) * DD + d]
            + w1 * vb[((t + e1) % LL) * DD + d]
            + w2 * vb[((t + e2) % LL) * DD + d];
    bf16 hi, lo; split_val(r, &hi, &lo);
    ahb[p] = hi; alb[p] = lo;
  }
}

// ---------------------------------------------------------------------------
// h = (h+a) - movavg25(h+a); h lives as split planes (hi+lo). In-place safe.
// ---------------------------------------------------------------------------
__global__ __launch_bounds__(256)
void decomp_add(bf16* __restrict__ hh, bf16* __restrict__ hl,
                const float* __restrict__ a) {
  int idx = blockIdx.x * blockDim.x + threadIdx.x;
  if (idx >= BB * DD) return;
  int b = idx >> 7, d = idx & 127;
  size_t base = (size_t)b * LL * DD + d;
  float x[LL];
#pragma unroll
  for (int t = 0; t < LL; t++)
    x[t] = __bfloat162float(hh[base + t * DD]) + __bfloat162float(hl[base + t * DD])
         + a[base + t * DD];
  float s = 13.0f * x[0];
#pragma unroll
  for (int u = 1; u <= 12; u++) s += x[u];
#pragma unroll
  for (int t = 0; t < LL; t++) {
    float val = x[t] - s * (1.0f / 25.0f);
    bf16 hi, lo; split_val(val, &hi, &lo);
    hh[base + t * DD] = hi;
    hl[base + t * DD] = lo;
    int add = (t + 13 > LL - 1) ? (LL - 1) : (t + 13);
    int sub = (t - 12 < 0) ? 0 : (t - 12);
    s += x[add] - x[sub];
  }
}

// ---------------------------------------------------------------------------
// my_Layernorm from planes -> planes (in-place per block is safe)
// ---------------------------------------------------------------------------
__global__ __launch_bounds__(256)
void ln_kernel(const bf16* __restrict__ ih, const bf16* __restrict__ il,
               const float* __restrict__ lw, const float* __restrict__ lb,
               bf16* __restrict__ oh, bf16* __restrict__ ol) {
  const int b = blockIdx.x;
  __shared__ float xs[LL][129];
  const int tid = threadIdx.x;
  const int wave = tid >> 6, lane = tid & 63;
  size_t base = (size_t)b * LL * DD;
  for (int t = wave; t < LL; t += 4) {
    float a0 = __bfloat162float(ih[base + t * DD + lane]) + __bfloat162float(il[base + t * DD + lane]);
    float a1 = __bfloat162float(ih[base + t * DD + 64 + lane]) + __bfloat162float(il[base + t * DD + 64 + lane]);
    float s = a0 + a1, ss = a0 * a0 + a1 * a1;
#pragma unroll
    for (int off = 32; off >= 1; off >>= 1) {
      s  += __shfl_down(s, off);
      ss += __shfl_down(ss, off);
    }
    s = __shfl(s, 0); ss = __shfl(ss, 0);
    float mu = s * (1.0f / 128.0f);
    float var = ss * (1.0f / 128.0f) - mu * mu;
    float inv = rsqrtf(var + 1e-5f);
    xs[t][lane]      = (a0 - mu) * inv * lw[lane]      + lb[lane];
    xs[t][64 + lane] = (a1 - mu) * inv * lw[64 + lane] + lb[64 + lane];
  }
  __syncthreads();
  if (tid < DD) {
    float cs = 0.f;
#pragma unroll
    for (int t = 0; t < LL; t++) cs += xs[t][tid];
    cs *= (1.0f / 36.0f);
#pragma unroll
    for (int t = 0; t < LL; t++) {
      float v = xs[t][tid] - cs;
      bf16 hi, lo; split_val(v, &hi, &lo);
      oh[base + t * DD + tid] = hi;
      ol[base + t * DD + tid] = lo;
    }
  }
}

// ---------------------------------------------------------------------------
// W23 = fc2_w @ fc3_w [13824,2]; row 13824 holds b23 = fc2_b@fc3_w + fc3_b.
// 4 waves/block, one row per wave.
// ---------------------------------------------------------------------------
__global__ __launch_bounds__(256)
void w23_kernel(const float* __restrict__ fc2w, const float* __restrict__ fc2b,
                const float* __restrict__ fc3w, const float* __restrict__ fc3b,
                float* __restrict__ W23) {
  int r = blockIdx.x * 4 + (threadIdx.x >> 6);
  int lane = threadIdx.x & 63;
  if (r > 13824) return;
  const float* row = (r < 13824) ? fc2w + (size_t)r * 4608 : fc2b;
  float a0 = 0.f, a1 = 0.f;
  for (int j = lane; j < 4608; j += 64) {
    float x = row[j];
    a0 += x * fc3w[2 * j];
    a1 += x * fc3w[2 * j + 1];
  }
#pragma unroll
  for (int off = 32; off >= 1; off >>= 1) {
    a0 += __shfl_down(a0, off);
    a1 += __shfl_down(a1, off);
  }
  if (lane == 0) {
    if (r == 13824) { a0 += fc3b[0]; a1 += fc3b[1]; }
    W23[2 * r] = a0; W23[2 * r + 1] = a1;
  }
}

// ---------------------------------------------------------------------------
// logits = z1 @ W23 + b23; softmax. Block per batch row.
// ---------------------------------------------------------------------------
__global__ __launch_bounds__(256)
void logits_softmax(const float* __restrict__ z1, const float* __restrict__ W23,
                    float* __restrict__ out) {
  const int b = blockIdx.x;
  const int tid = threadIdx.x;
  const float* zb = z1 + (size_t)b * 13824;
  float a0 = 0.f, a1 = 0.f;
  for (int i = tid; i < 13824; i += 256) {
    float x = zb[i];
    a0 += x * W23[2 * i];
    a1 += x * W23[2 * i + 1];
  }
  __shared__ float r0[4], r1[4];
#pragma unroll
  for (int off = 32; off >= 1; off >>= 1) {
    a0 += __shfl_down(a0, off);
    a1 += __shfl_down(a1, off);
  }
  int wave = tid >> 6, lane = tid & 63;
  if (lane == 0) { r0[wave] = a0; r1[wave] = a1; }
  __syncthreads();
  if (tid == 0) {
    float l0 = r0[0] + r0[1] + r0[2] + r0[3] + W23[2 * 13824];
    float l1 = r1[0] + r1[1] + r1[2] + r1[3] + W23[2 * 13824 + 1];
    float m = fmaxf(l0, l1);
    float e0 = expf(l0 - m), e1 = expf(l1 - m);
    float inv = 1.0f / (e0 + e1);
    out[(size_t)b * 2]     = e0 * inv;
    out[(size_t)b * 2 + 1] = e1 * inv;
  }
}

// ---------------------------------------------------------------------------
extern "C" void kernel_launch(void* const* d_in, const int* in_sizes, int n_in,
                              void* d_out, int out_size, void* d_ws, size_t ws_size,
                              hipStream_t stream) {
  const float* x        = (const float*)d_in[0];
  const float* linear_w = (const float*)d_in[1];
  const float* linear_b = (const float*)d_in[2];
  const float* Wq = (const float*)d_in[3];
  const float* bq = (const float*)d_in[4];
  const float* Wk = (const float*)d_in[5];
  const float* bk = (const float*)d_in[6];
  const float* Wv = (const float*)d_in[7];
  const float* bv = (const float*)d_in[8];
  const float* Wo = (const float*)d_in[9];
  const float* bo = (const float*)d_in[10];
  const float* conv1_w = (const float*)d_in[11];
  const float* conv2_w = (const float*)d_in[12];
  const float* ln_w = (const float*)d_in[13];
  const float* ln_b = (const float*)d_in[14];
  const float* fc1_w = (const float*)d_in[15];
  const float* fc1_b = (const float*)d_in[16];
  const float* fc2_w = (const float*)d_in[17];
  const float* fc2_b = (const float*)d_in[18];
  const float* fc3_w = (const float*)d_in[19];
  const float* fc3_b = (const float*)d_in[20];
  float* out = (float*)d_out;

  // Layout in units of SB = SFL*4 bytes = 75.5 MB:
  // [0,1) hb planes | [1,3) qk fp32 | [3,4) v fp32 | [4,5) agg planes |
  // [5,6) abuf fp32 | [6,10) mid planes | [10SB..) small weights.
  // Head phase reuse: fc1T planes at 1SB (255MB < 4SB), z1 fp32 at 5SB (226MB).
  char* base = (char*)d_ws;
  const size_t SB = SFL * 4;
  bf16*  hb_hi  = (bf16*)base;
  bf16*  hb_lo  = hb_hi + SFL;
  float* qk     = (float*)(base + 1 * SB);
  float* v      = (float*)(base + 3 * SB);
  bf16*  agg_hi = (bf16*)(base + 4 * SB);
  bf16*  agg_lo = agg_hi + SFL;
  float* abuf   = (float*)(base + 5 * SB);
  bf16*  mid_hi = (bf16*)(base + 6 * SB);
  bf16*  mid_lo = mid_hi + 4 * SFL;
  bf16*  wqkT_hi = (bf16*)(base + 10 * SB);
  bf16*  wqkT_lo = wqkT_hi + 8 * 32768;
  bf16*  wvT_hi  = wqkT_lo + 8 * 32768;
  bf16*  wvT_lo  = wvT_hi + 8 * 16384;
  bf16*  woT_hi  = wvT_lo + 8 * 16384;
  bf16*  woT_lo  = woT_hi + 8 * 16384;
  bf16*  c1T_hi  = woT_lo + 8 * 16384;
  bf16*  c1T_lo  = c1T_hi + 8 * 65536;
  bf16*  c2T_hi  = c1T_lo + 8 * 65536;
  bf16*  c2T_lo  = c2T_hi + 8 * 65536;
  float* W23     = (float*)(c2T_lo + 8 * 65536);     // 13825*2 floats
  float* qkbias  = W23 + 13825 * 2 + 2;              // 8*256 floats
  // head-phase aliases
  bf16*  fc1T_hi = (bf16*)(base + 1 * SB);
  bf16*  fc1T_lo = fc1T_hi + (size_t)13824 * 4608;
  float* z1      = (float*)(base + 5 * SB);

  dim3 blk(256);

  // Embed: abuf = x @ linear_w + b (fp32, K=36), then split into planes.
  gemm_f32<0><<<dim3(72, 64), blk, 0, stream>>>(x, linear_w, linear_b, abuf, BB, 4608, 36);
  split_cast<<<dim3((unsigned)(SFL / 256)), blk, 0, stream>>>(abuf, hb_hi, hb_lo, SFL);

  // Weight prep
  pack_qk_bias<<<dim3(8), blk, 0, stream>>>(bq, bk, qkbias);
  transpose_split<<<dim3(4, 4, 8),  blk, 0, stream>>>(Wq, wqkT_hi,         wqkT_lo,         128, 128, 128, 16384, 32768);
  transpose_split<<<dim3(4, 4, 8),  blk, 0, stream>>>(Wk, wqkT_hi + 16384, wqkT_lo + 16384, 128, 128, 128, 16384, 32768);
  transpose_split<<<dim3(4, 4, 8),  blk, 0, stream>>>(Wv, wvT_hi, wvT_lo, 128, 128, 128, 16384, 16384);
  transpose_split<<<dim3(4, 4, 8),  blk, 0, stream>>>(Wo, woT_hi, woT_lo, 128, 128, 128, 16384, 16384);
  transpose_split<<<dim3(16, 4, 8), blk, 0, stream>>>(conv1_w, c1T_hi, c1T_lo, 128, 512, 512, 65536, 65536);
  transpose_split<<<dim3(4, 16, 8), blk, 0, stream>>>(conv2_w, c2T_hi, c2T_lo, 512, 128, 128, 65536, 65536);

  for (int i = 0; i < ELAYERS; i++) {
    const size_t o32 = (size_t)i * 32768;
    const size_t o16 = (size_t)i * 16384;
    const size_t o64 = (size_t)i * 65536;
    // fused q||k projection (split MFMA, error ~2^-17 — safe for top-3)
    gemm_split<0,0><<<dim3(2, 1152), blk, 0, stream>>>(
        hb_hi, hb_lo, wqkT_hi + o32, wqkT_lo + o32, qkbias + i * 256,
        qk, nullptr, nullptr, MROW, 256, DD, DD, DD);
    // v projection
    gemm_split<0,0><<<dim3(1, 1152), blk, 0, stream>>>(
        hb_hi, hb_lo, wvT_hi + o16, wvT_lo + o16, bv + i * DD,
        v, nullptr, nullptr, MROW, DD, DD, DD, DD);
    autocorr_kernel<<<dim3(BB), blk, 0, stream>>>(qk, v, agg_hi, agg_lo);
    // out-proj
    gemm_split<0,0><<<dim3(1, 1152), blk, 0, stream>>>(
        agg_hi, agg_lo, woT_hi + o16, woT_lo + o16, bo + i * DD,
        abuf, nullptr, nullptr, MROW, DD, DD, DD, DD);
    decomp_add<<<dim3((BB * DD) / 256), blk, 0, stream>>>(hb_hi, hb_lo, abuf);
    // FFN (single launches)
    gemm_split<1,1><<<dim3(4, 1152), blk, 0, stream>>>(
        hb_hi, hb_lo, c1T_hi + o64, c1T_lo + o64, nullptr,
        nullptr, mid_hi, mid_lo, MROW, DFF, DD, DD, DD);
    gemm_split<0,0><<<dim3(1, 1152), blk, 0, stream>>>(
        mid_hi, mid_lo, c2T_hi + o64, c2T_lo + o64, nullptr,
        abuf, nullptr, nullptr, MROW, DD, DFF, DFF, DFF);
    decomp_add<<<dim3((BB * DD) / 256), blk, 0, stream>>>(hb_hi, hb_lo, abuf);
  }

  // LN -> flat planes (in place in hb)
  ln_kernel<<<dim3(BB), blk, 0, stream>>>(hb_hi, hb_lo, ln_w, ln_b, hb_hi, hb_lo);

  // Head: fc1 (split MFMA, gelu) -> z1 fp32; fc2∘fc3 collapsed into W23.
  transpose_split<<<dim3(432, 144, 1), blk, 0, stream>>>(fc1_w, fc1T_hi, fc1T_lo, 4608, 13824, 13824, 0, 0);
  gemm_split<1,0><<<dim3(108, 32), blk, 0, stream>>>(
      hb_hi, hb_lo, fc1T_hi, fc1T_lo, fc1_b,
      z1, nullptr, nullptr, BB, 13824, 4608, 4608, 4608);
  w23_kernel<<<dim3(3457), blk, 0, stream>>>(fc2_w, fc2_b, fc3_w, fc3_b, W23);
  logits_softmax<<<dim3(BB), blk, 0, stream>>>(z1, W23, out);
}